// Round 9
// baseline (468.498 us; speedup 1.0000x reference)
//
#include <hip/hip_runtime.h>
#include <hip/hip_bf16.h>

#define NNODES 50000
#define NEDGES 800000
#define DF 128
#define KW 1152                // K per branch: 128 silu + 1024 spline (native order)
#define EPS 0.001f
#define XSS 132                // Xs row stride in bf16 elems (128 + 4 pad)
#define NB 196                 // scan blocks: 196*256 >= 50000
#define PSZ (NNODES * 32)      // bf16 elems per feature panel

typedef __bf16 bf16x8 __attribute__((ext_vector_type(8)));
typedef __bf16 bf16x4 __attribute__((ext_vector_type(4)));
typedef float  f32x4  __attribute__((ext_vector_type(4)));
typedef unsigned long ulongx2 __attribute__((ext_vector_type(2)));

// ---- weight pre-transform: wt[o][k]; k<128 -> bw[o][k]; else sw[o][k-128] ----
__global__ void build_wt(const float* __restrict__ bwl, const float* __restrict__ swl,
                         const float* __restrict__ bwc, const float* __restrict__ swc,
                         __bf16* __restrict__ wtl, __bf16* __restrict__ wtc) {
    int gid = blockIdx.x * 256 + threadIdx.x;      // 128*1152 threads in x
    const float* bw = blockIdx.y ? bwc : bwl;
    const float* sw = blockIdx.y ? swc : swl;
    __bf16*      wt = blockIdx.y ? wtc : wtl;
    int o = gid / KW;
    int k = gid - o * KW;
    float v = (k < 128) ? bw[o * DF + k] : sw[o * 1024 + (k - 128)];
    wt[gid] = (__bf16)v;
}

// ---- bf16 shadow of x in PANEL layout: xq[f>>5][n][f&31] ----
__global__ void cast_x(const float* __restrict__ x, __bf16* __restrict__ xq) {
    int i = blockIdx.x * 256 + threadIdx.x;        // 800,000 threads, 8 elems each
    int n  = i >> 4;
    int f0 = (i & 15) * 8;
    f32x4 a = ((const f32x4*)x)[2 * i];
    f32x4 b = ((const f32x4*)x)[2 * i + 1];
    bf16x8 o;
    o[0] = (__bf16)a[0]; o[1] = (__bf16)a[1]; o[2] = (__bf16)a[2]; o[3] = (__bf16)a[3];
    o[4] = (__bf16)b[0]; o[5] = (__bf16)b[1]; o[6] = (__bf16)b[2]; o[7] = (__bf16)b[3];
    *(bf16x8*)(xq + (size_t)(f0 >> 5) * PSZ + (size_t)n * 32 + (f0 & 31)) = o;
}

// ---------------- CSR build ----------------
__global__ void deg_count(const int* __restrict__ ei, int* __restrict__ deg) {
    int e = blockIdx.x * 256 + threadIdx.x;
    if (e >= NEDGES) return;
    atomicAdd(&deg[ei[NEDGES + e]], 1);
}

// 3-kernel multi-block exclusive scan of deg -> rowptr
__global__ void scan_part(const int* __restrict__ deg, int* __restrict__ bsum) {
    __shared__ int red[256];
    int t = threadIdx.x;
    int i = blockIdx.x * 256 + t;
    red[t] = (i < NNODES) ? deg[i] : 0;
    __syncthreads();
    for (int off = 128; off > 0; off >>= 1) {
        if (t < off) red[t] += red[t + off];
        __syncthreads();
    }
    if (t == 0) bsum[blockIdx.x] = red[0];
}

__global__ void scan_bsum(const int* __restrict__ bsum, int* __restrict__ boff) {
    __shared__ int buf[256];
    int t = threadIdx.x;
    int v = (t < NB) ? bsum[t] : 0;
    buf[t] = v;
    __syncthreads();
    for (int off = 1; off < 256; off <<= 1) {
        int x = (t >= off) ? buf[t - off] : 0;
        __syncthreads();
        buf[t] += x;
        __syncthreads();
    }
    if (t <= NB) boff[t] = buf[t] - ((t < NB) ? bsum[t] : 0);   // exclusive; boff[NB]=total
}

__global__ void scan_final(const int* __restrict__ deg, const int* __restrict__ boff,
                           int* __restrict__ rowptr) {
    __shared__ int buf[256];
    int t = threadIdx.x;
    int i = blockIdx.x * 256 + t;
    int v = (i < NNODES) ? deg[i] : 0;
    buf[t] = v;
    __syncthreads();
    for (int off = 1; off < 256; off <<= 1) {
        int x = (t >= off) ? buf[t - off] : 0;
        __syncthreads();
        buf[t] += x;
        __syncthreads();
    }
    if (i < NNODES) rowptr[i] = buf[t] - v + boff[blockIdx.x];
    if (blockIdx.x == 0 && t == 0) rowptr[NNODES] = boff[NB];
}

__global__ void fill_csr(const int* __restrict__ ei, const int* __restrict__ deg,
                         const int* __restrict__ rowptr, int* __restrict__ cnt,
                         int2* __restrict__ esw) {
    int e = blockIdx.x * 256 + threadIdx.x;
    if (e >= NEDGES) return;
    int s = ei[e];
    int d = ei[NEDGES + e];
    float w = rsqrtf((float)(deg[s] + 1)) * rsqrtf((float)(deg[d] + 1));
    int p = rowptr[d] + atomicAdd(&cnt[d], 1);
    esw[p] = make_int2(s, __float_as_int(w));
}

// ---- aggregation, panel decomposition: wave = (4 nodes, 1 panel); 8 lanes/edge ----
// lane l: edge-slot = l>>3, feature = (l&7)*4 within the 32-feature panel.
// Butterfly xor-reduce over slots; lanes 0..7 write the 64B panel row.
#define GPW 4
__global__ __launch_bounds__(256) void agg_gather(
        const int* __restrict__ rowptr, const int2* __restrict__ esw,
        const __bf16* __restrict__ xq, __bf16* __restrict__ aggq) {
    const int l    = threadIdx.x & 63;
    const int wv   = threadIdx.x >> 6;
    const int slot = l >> 3;
    const int fo   = (l & 7) * 4;
    const int pz   = blockIdx.y;
    const __bf16* xp = xq   + (size_t)pz * PSZ;
    __bf16*       ap = aggq + (size_t)pz * PSZ;
    const int nb = (blockIdx.x * 4 + wv) * GPW;
#pragma unroll
    for (int g = 0; g < GPW; ++g) {
        const int n = nb + g;
        if (n >= NNODES) break;
        int ps = rowptr[n];
        const int pe = rowptr[n + 1];
        f32x4 acc = {0.0f, 0.0f, 0.0f, 0.0f};
        for (int p0 = ps; p0 < pe; p0 += 8) {
            int e = p0 + slot;
            bool valid = e < pe;
            int2 ev = esw[valid ? e : ps];
            float w = valid ? __int_as_float(ev.y) : 0.0f;
            bf16x4 v = *(const bf16x4*)(xp + (size_t)ev.x * 32 + fo);
#pragma unroll
            for (int j = 0; j < 4; ++j) acc[j] += w * (float)v[j];
        }
#pragma unroll
        for (int m = 8; m <= 32; m <<= 1) {
#pragma unroll
            for (int j = 0; j < 4; ++j) acc[j] += __shfl_xor(acc[j], m, 64);
        }
        if (l < 8) {
            bf16x4 o;
#pragma unroll
            for (int j = 0; j < 4; ++j) o[j] = (__bf16)acc[j];
            *(bf16x4*)(ap + (size_t)n * 32 + l * 4) = o;
        }
    }
}

// ---- fused Euler step: out = h + EPS*(kanl(h) + kanc(agg)) -------------------
// Concatenated K = 72 chunks of 32. t<36: branch L (xq, wtl); else C (aggq, wtc).
// Per branch: ck<4 silu (i = ck*32+kk); else spline k = 128+i*8+b, i=(ck-4)*4+q, b=j.
// ROW-SPLIT waves: wave w = rows [w*16, +16) x ALL 128 cols; expansion once/element.
// A built in-register (perm pack + funnel shift); x from per-branch LDS tile (panels).
// B LDS double-buffered w/ register prefetch, 1 barrier/chunk.
__global__ __launch_bounds__(256, 4) void kan_step(
        const float* __restrict__ h,          // f32 state, row-major (epilogue read)
        const __bf16* __restrict__ xq,        // bf16 shadow of h, panels (branch L)
        const __bf16* __restrict__ aggq,      // bf16 aggregate, panels (branch C)
        const __bf16* __restrict__ wtl, const __bf16* __restrict__ wtc,
        float* __restrict__ out, __bf16* __restrict__ outq) {
    __shared__ __bf16 Bs[2][128 * 40];       // [buf][o][kk], stride 40
    __shared__ __bf16 Xs[64 * XSS];          // x-tile for current branch (row-major)

    const int tid  = threadIdx.x;
    const int lane = tid & 63;
    const int w    = tid >> 6;               // wave -> rows [w*16, +16)
    const int q    = lane >> 4, l15 = lane & 15;
    const int n0   = blockIdx.x * 64;

    const int so = tid & 127, sh = tid >> 7;         // B staging
    const int bbase = so * 40 + sh * 16;
    const size_t wrow = (size_t)so * KW + sh * 16;

    const int xrow = tid >> 2, xseg = tid & 3;       // X staging: one 64B panel row
    const bool xok = (n0 + xrow) < NNODES;
    const size_t xgoff = (size_t)xseg * PSZ + (size_t)(n0 + xrow) * 32;
    const int xloff = xrow * XSS + xseg * 32;

    const int myrow = w * 16 + l15;                  // this lane's expansion row

    f32x4 acc[8] = {};
    uint4 g0, g1;                                    // B prefetch regs

    auto stage_x = [&](const __bf16* src) {
        uint4 v0 = {}, v1 = {}, v2 = {}, v3 = {};
        if (xok) {
            const uint4* g = (const uint4*)(src + xgoff);
            v0 = g[0]; v1 = g[1]; v2 = g[2]; v3 = g[3];
        }
        *(uint4*)&Xs[xloff]      = v0;
        *(uint4*)&Xs[xloff + 8]  = v1;
        *(uint4*)&Xs[xloff + 16] = v2;
        *(uint4*)&Xs[xloff + 24] = v3;
    };

    auto loadB = [&](int tn) {
        const __bf16* wtp = (tn >= 36) ? wtc : wtl;
        const int ck = (tn >= 36) ? tn - 36 : tn;
        const uint4* gp = (const uint4*)(wtp + wrow + ck * 32);
        g0 = gp[0]; g1 = gp[1];
    };
    auto writeB = [&](int buf) {
        *(uint4*)&Bs[buf][bbase]     = g0;
        *(uint4*)&Bs[buf][bbase + 8] = g1;
    };

    auto spline_pack = [&](float x) -> bf16x8 {
        float f  = __builtin_fmaf(x, 2.5f, 5.5f);    // (x+2.2)/0.4
        float fi = floorf(f);
        int  idx = (int)fi;
        float u  = f - fi;
        float u2 = u * u, u3 = u2 * u;
        float om = 1.0f - u;
        float Wa = u3 * (1.0f / 6.0f);
        float Wb = (((-3.0f * u + 3.0f) * u + 3.0f) * u + 1.0f) * (1.0f / 6.0f);
        float Wc = ((3.0f * u - 6.0f) * u2 + 4.0f) * (1.0f / 6.0f);
        float Wd = om * om * om * (1.0f / 6.0f);
        // truncating f32->bf16 pack: lo16=Wd, hi16=Wc (and Wb/Wa) via v_perm_b32
        unsigned lo32 = __builtin_amdgcn_perm(__builtin_bit_cast(unsigned, Wc),
                                              __builtin_bit_cast(unsigned, Wd), 0x07060302u);
        unsigned hi32 = __builtin_amdgcn_perm(__builtin_bit_cast(unsigned, Wa),
                                              __builtin_bit_cast(unsigned, Wb), 0x07060302u);
        unsigned long p = (unsigned long)lo32 | ((unsigned long)hi32 << 32);
        int tt = idx - 3;                            // slot of Wd in [0,8)
        unsigned long lo, hi;
        if (tt >= 0) {
            int s = (tt & 3) * 16;
            unsigned long sv = p << s;
            unsigned long cr = (p >> (63 - s)) >> 1; // == p>>(64-s), s==0 safe
            bool hh = tt >= 4;
            lo = hh ? 0ul : sv;
            hi = hh ? sv : cr;
            if (tt >= 8) { lo = 0; hi = 0; }
        } else {
            int s = (-tt) * 16;
            lo = (tt >= -3) ? (p >> (s & 63)) : 0ul;
            hi = 0;
        }
        ulongx2 r; r[0] = lo; r[1] = hi;
        return __builtin_bit_cast(bf16x8, r);
    };

    auto silu8 = [&](const __bf16* xs) -> bf16x8 {
        bf16x8 v = *(const bf16x8*)xs;
        bf16x8 o;
#pragma unroll
        for (int j = 0; j < 8; ++j) {
            float x = (float)v[j];
            o[j] = (__bf16)(x / (1.0f + __expf(-x)));
        }
        return o;
    };

    stage_x(xq);
    loadB(0); writeB(0);
    __syncthreads();

#pragma unroll 2
    for (int t = 0; t < 72; ++t) {
        const int buf = t & 1;
        const bool more = t + 1 < 72;
        if (more) loadB(t + 1);                      // global B prefetch in flight

        const int ck = (t >= 36) ? t - 36 : t;
        bf16x8 a;
        if (ck < 4) {
            a = silu8(&Xs[myrow * XSS + ck * 32 + q * 8]);
        } else {
            unsigned short u0 = *(const unsigned short*)&Xs[myrow * XSS + (ck - 4) * 4 + q];
            a = spline_pack(__builtin_bit_cast(float, (unsigned)u0 << 16));
        }

        bf16x8 bF[8];
#pragma unroll
        for (int nj = 0; nj < 8; ++nj)
            bF[nj] = *(const bf16x8*)&Bs[buf][(nj * 16 + l15) * 40 + q * 8];
#pragma unroll
        for (int nj = 0; nj < 8; ++nj)
            acc[nj] = __builtin_amdgcn_mfma_f32_16x16x32_bf16(a, bF[nj], acc[nj], 0, 0, 0);

        if (t == 35) {                               // branch switch: restage x-tile
            __syncthreads();                         // all branch-L Xs reads done
            stage_x(aggq);
        }
        if (more) writeB(buf ^ 1);
        __syncthreads();
    }

    // epilogue: Euler; D layout row = q*4+r, col = l15 (m89-verified)
#pragma unroll
    for (int nj = 0; nj < 8; ++nj) {
#pragma unroll
        for (int r = 0; r < 4; ++r) {
            int row = n0 + w * 16 + q * 4 + r;
            int col = nj * 16 + l15;
            if (row < NNODES) {
                size_t idx = (size_t)row * DF + col;
                float v = h[idx] + EPS * acc[nj][r];
                out[idx] = v;
                outq[(size_t)(col >> 5) * PSZ + (size_t)row * 32 + (col & 31)] = (__bf16)v;
            }
        }
    }
}

extern "C" void kernel_launch(void* const* d_in, const int* in_sizes, int n_in,
                              void* d_out, int out_size, void* d_ws, size_t ws_size,
                              hipStream_t stream) {
    const float* x   = (const float*)d_in[0];
    const int*   ei  = (const int*)d_in[1];     // edge_index [2,E] int32
    const float* bwl = (const float*)d_in[2];
    const float* swl = (const float*)d_in[3];
    const float* bwc = (const float*)d_in[4];
    const float* swc = (const float*)d_in[5];
    float* out = (float*)d_out;

    char* ws = (char*)d_ws;
    int*    deg    = (int*)  (ws + 0);            //   200,000
    int*    cnt    = (int*)  (ws + 200000);       //   200,000 (adjacent: single memset)
    int*    rowptr = (int*)  (ws + 400000);       //   200,004
    int*    bsum   = (int*)  (ws + 600064);       //       784
    int*    boff   = (int*)  (ws + 600896);       //       788
    int2*   esw    = (int2*) (ws + 601728);       // 6,400,000 (fused {src, w})
    __bf16* xq     = (__bf16*)(ws + 7001728);     // 12,800,000 (panel layout)
    __bf16* aggq   = (__bf16*)(ws + 19801728);    // 12,800,000 (panel layout)
    __bf16* wtl    = (__bf16*)(ws + 32601728);    //    294,912
    __bf16* wtc    = (__bf16*)(ws + 32896640);    //    294,912  (total ~33.2 MB)

    build_wt<<<dim3((DF * KW) / 256, 2), 256, 0, stream>>>(bwl, swl, bwc, swc, wtl, wtc);
    cast_x<<<3125, 256, 0, stream>>>(x, xq);

    hipMemsetAsync(deg, 0, 400000, stream);       // deg + cnt
    deg_count<<<3125, 256, 0, stream>>>(ei, deg);
    scan_part<<<NB, 256, 0, stream>>>(deg, bsum);
    scan_bsum<<<1, 256, 0, stream>>>(bsum, boff);
    scan_final<<<NB, 256, 0, stream>>>(deg, boff, rowptr);
    fill_csr<<<3125, 256, 0, stream>>>(ei, deg, rowptr, cnt, esw);

    const int gemm_grid = (NNODES + 63) / 64;     // 782
    const float* h = x;
    for (int step = 0; step < 2; ++step) {        // delta_t = 2
        agg_gather<<<dim3(3125, 4), 256, 0, stream>>>(rowptr, esw, xq, aggq);
        kan_step<<<gemm_grid, 256, 0, stream>>>(h, xq, aggq, wtl, wtc, out, xq);
        h = out;
    }
}